// Round 1
// baseline (971.560 us; speedup 1.0000x reference)
//
#include <hip/hip_runtime.h>
#include <stdint.h>

#define DIM   2048
#define BATCH 4
#define SEQ   4096
#define NTOK  (BATCH*SEQ)      // 16384
#define NCH   32               // cumsum chunks per sequence
#define CHUNK (SEQ/NCH)        // 128 tokens per chunk

// workspace layout (bytes); total ~353 MiB
#define XB_BYTES   ((size_t)NTOK*DIM*2)          // x in bf16
#define WB_BYTES   ((size_t)4*DIM*DIM*2)         // 4 weights in bf16
#define Y_BYTES    ((size_t)4*NTOK*DIM*2)        // q,k,v,g raw linear outs, bf16
#define PART_BYTES ((size_t)BATCH*NCH*DIM*4)     // chunk partial sums, fp32

typedef __bf16 bf16x8 __attribute__((ext_vector_type(8)));
typedef float  f32x4  __attribute__((ext_vector_type(4)));

__device__ __forceinline__ unsigned short f2bf(float f) {
  unsigned int u = __float_as_uint(f);
  u += 0x7FFFu + ((u >> 16) & 1u);          // round-to-nearest-even
  return (unsigned short)(u >> 16);
}
__device__ __forceinline__ float bflo(unsigned int u){ return __uint_as_float(u << 16); }
__device__ __forceinline__ float bfhi(unsigned int u){ return __uint_as_float(u & 0xFFFF0000u); }
__device__ __forceinline__ float sigm(float x){ return 1.0f/(1.0f + __expf(-x)); }

__device__ __forceinline__ void gload16(const void* g, void* l) {
  __builtin_amdgcn_global_load_lds((const __attribute__((address_space(1))) unsigned int*)g,
                                   (__attribute__((address_space(3))) unsigned int*)l,
                                   16, 0, 0);
}

// ---------------- fp32 -> bf16 conversion (8 elems/thread) ----------------
__global__ void cvt_kernel(const float* __restrict__ src,
                           unsigned short* __restrict__ dst, int n8) {
  int i = blockIdx.x * blockDim.x + threadIdx.x;
  if (i >= n8) return;
  const float4* s4 = (const float4*)src;
  float4 a = s4[2*i], b = s4[2*i+1];
  uint4 o;
  o.x = (unsigned int)f2bf(a.x) | ((unsigned int)f2bf(a.y) << 16);
  o.y = (unsigned int)f2bf(a.z) | ((unsigned int)f2bf(a.w) << 16);
  o.z = (unsigned int)f2bf(b.x) | ((unsigned int)f2bf(b.y) << 16);
  o.w = (unsigned int)f2bf(b.z) | ((unsigned int)f2bf(b.w) << 16);
  ((uint4*)dst)[i] = o;
}

// ---------------- m97-style bf16 GEMM: Y[z] = x @ W[z]^T + b[z] ----------------
// grid (DIM/128, NTOK/128, 4), block 256 (4 waves, each owns 64x64 of the tile)
__global__ __launch_bounds__(256, 2)
void gemm_kernel(const unsigned short* __restrict__ xb,
                 const unsigned short* __restrict__ Wall,
                 const float* __restrict__ bq, const float* __restrict__ bk,
                 const float* __restrict__ bv, const float* __restrict__ bg,
                 unsigned short* __restrict__ Yall) {
  __shared__ __align__(16) unsigned short ldsA[128*32];
  __shared__ __align__(16) unsigned short ldsB[128*32];

  const int t  = threadIdx.x;
  const int e0 = blockIdx.x * 128;
  const int m0 = blockIdx.y * 128;
  const int z  = blockIdx.z;
  const unsigned short* Wz = Wall + (size_t)z * DIM * DIM;

  // --- staging: 512 chunks of 16B per tile per matrix; 2 per thread.
  // XOR-swizzle the *source* column-chunk so fragment ds_read_b128s are
  // only 4-way bank-conflicted (LDS dest of global_load_lds cannot be padded).
  const int r0 = t >> 2;                    // row 0..63 (second round: +64)
  const int cc = (t & 3) ^ (r0 & 3);        // swizzled 8-elem column chunk
  const unsigned short* gA0 = xb + (size_t)(m0 + r0) * DIM + cc * 8;
  const unsigned short* gA1 = gA0 + (size_t)64 * DIM;   // (r0+64)&3 == r0&3
  const unsigned short* gB0 = Wz + (size_t)(e0 + r0) * DIM + cc * 8;
  const unsigned short* gB1 = gB0 + (size_t)64 * DIM;
  unsigned short* lA0 = &ldsA[(size_t)t * 8];
  unsigned short* lA1 = &ldsA[(size_t)(t + 256) * 8];
  unsigned short* lB0 = &ldsB[(size_t)t * 8];
  unsigned short* lB1 = &ldsB[(size_t)(t + 256) * 8];

  // --- fragment read offsets (slot(r,cc) = r*4 + (cc ^ (r&3)), in 8-ushort units)
  const int lane = t & 63;
  const int wave = t >> 6;
  const int wm = wave >> 1, wn = wave & 1;
  const int lr = lane & 15, lq = lane >> 4;
  const int swz8 = (lq ^ (lr & 3)) * 8;
  int aoff[4], boff[4];
  #pragma unroll
  for (int i = 0; i < 4; i++) aoff[i] = (wm*64 + i*16 + lr)*32 + swz8;
  #pragma unroll
  for (int j = 0; j < 4; j++) boff[j] = (wn*64 + j*16 + lr)*32 + swz8;

  f32x4 acc[4][4];
  #pragma unroll
  for (int i = 0; i < 4; i++)
    #pragma unroll
    for (int j = 0; j < 4; j++)
      acc[i][j] = (f32x4){0.f, 0.f, 0.f, 0.f};

  for (int kt = 0; kt < DIM/32; ++kt) {
    __syncthreads();                        // prev iter's ds_reads done
    const int ko = kt * 32;
    gload16(gA0 + ko, lA0);
    gload16(gA1 + ko, lA1);
    gload16(gB0 + ko, lB0);
    gload16(gB1 + ko, lB1);
    __syncthreads();                        // compiler drains vmcnt here

    bf16x8 a[4], b[4];
    #pragma unroll
    for (int i = 0; i < 4; i++) a[i] = *(const bf16x8*)&ldsA[aoff[i]];
    #pragma unroll
    for (int j = 0; j < 4; j++) b[j] = *(const bf16x8*)&ldsB[boff[j]];
    #pragma unroll
    for (int i = 0; i < 4; i++)
      #pragma unroll
      for (int j = 0; j < 4; j++)
        acc[i][j] = __builtin_amdgcn_mfma_f32_16x16x32_bf16(a[i], b[j], acc[i][j], 0, 0, 0);
  }

  // epilogue: C/D layout col=lane&15 (=> e), row=(lane>>4)*4+reg (=> token m)
  const float* bias = (z == 0) ? bq : (z == 1) ? bk : (z == 2) ? bv : bg;
  unsigned short* Y = Yall + (size_t)z * NTOK * DIM;
  #pragma unroll
  for (int j = 0; j < 4; j++) {
    const int e = e0 + wn*64 + j*16 + lr;
    const float bb = bias[e];
    #pragma unroll
    for (int i = 0; i < 4; i++) {
      const int mb = m0 + wm*64 + i*16 + lq*4;
      #pragma unroll
      for (int r = 0; r < 4; r++)
        Y[(size_t)(mb + r) * DIM + e] = f2bf(acc[i][j][r] + bb);
    }
  }
}

// ---------------- phase 1: per-chunk partial sums of k*v ----------------
// grid (DIM/512, NCH, BATCH), block 256; 2 channels per thread
__global__ void chunk_sum_kernel(const unsigned short* __restrict__ Yk,
                                 const unsigned short* __restrict__ Yv,
                                 float* __restrict__ partial) {
  const int d = (blockIdx.x * 256 + threadIdx.x) * 2;
  const int c = blockIdx.y, b = blockIdx.z;
  const size_t base = (size_t)(b*SEQ + c*CHUNK) * DIM + d;
  const unsigned int* pk = (const unsigned int*)(Yk + base);
  const unsigned int* pv = (const unsigned int*)(Yv + base);
  float s0 = 0.f, s1 = 0.f;
  #pragma unroll 8
  for (int i = 0; i < CHUNK; i++) {
    unsigned int ku = pk[i*(DIM/2)];
    unsigned int vu = pv[i*(DIM/2)];
    s0 += bflo(ku) * bflo(vu);
    s1 += bfhi(ku) * bfhi(vu);
  }
  float2* pp = (float2*)(partial + (size_t)(b*NCH + c)*DIM + d);
  *pp = make_float2(s0, s1);
}

// ---------------- phase 2: exclusive scan of partials (tiny) ----------------
__global__ void scan_kernel(float* __restrict__ partial) {
  const int idx = blockIdx.x * blockDim.x + threadIdx.x;  // 0..BATCH*DIM-1
  const int b = idx >> 11;         // / DIM
  const int d = idx & (DIM - 1);
  float run = 0.f;
  for (int c = 0; c < NCH; c++) {
    float* p = partial + (size_t)(b*NCH + c)*DIM + d;
    float tv = *p;
    *p = run;
    run += tv;
  }
}

// ---------------- phase 3: cumsum within chunk + gate + output ----------------
// grid (DIM/512, NCH, BATCH), block 256; 2 channels per thread
__global__ void final_kernel(const unsigned short* __restrict__ Yq,
                             const unsigned short* __restrict__ Yk,
                             const unsigned short* __restrict__ Yv,
                             const unsigned short* __restrict__ Yg,
                             const float* __restrict__ partial,
                             float* __restrict__ out) {
  const int d = (blockIdx.x * 256 + threadIdx.x) * 2;
  const int c = blockIdx.y, b = blockIdx.z;
  const size_t base = (size_t)(b*SEQ + c*CHUNK) * DIM + d;
  float2 st = *(const float2*)(partial + (size_t)(b*NCH + c)*DIM + d);
  float s0 = st.x, s1 = st.y;
  const unsigned int* pq = (const unsigned int*)(Yq + base);
  const unsigned int* pk = (const unsigned int*)(Yk + base);
  const unsigned int* pv = (const unsigned int*)(Yv + base);
  const unsigned int* pg = (const unsigned int*)(Yg + base);
  float2* po = (float2*)(out + base);
  #pragma unroll 4
  for (int i = 0; i < CHUNK; i++) {
    unsigned int ku = pk[i*(DIM/2)];
    unsigned int vu = pv[i*(DIM/2)];
    unsigned int qu = pq[i*(DIM/2)];
    unsigned int gu = pg[i*(DIM/2)];
    s0 += bflo(ku) * bflo(vu);
    s1 += bfhi(ku) * bfhi(vu);
    float o0 = bflo(qu) * s0 * sigm(bflo(gu));
    float o1 = bfhi(qu) * s1 * sigm(bfhi(gu));
    po[i*(DIM/2)] = make_float2(o0, o1);
  }
}

extern "C" void kernel_launch(void* const* d_in, const int* in_sizes, int n_in,
                              void* d_out, int out_size, void* d_ws, size_t ws_size,
                              hipStream_t stream) {
  const float* x  = (const float*)d_in[0];
  const float* Wq = (const float*)d_in[1];
  const float* bq = (const float*)d_in[2];
  const float* Wk = (const float*)d_in[3];
  const float* bk = (const float*)d_in[4];
  const float* Wv = (const float*)d_in[5];
  const float* bv = (const float*)d_in[6];
  const float* Wg = (const float*)d_in[7];
  const float* bg = (const float*)d_in[8];
  float* out = (float*)d_out;

  char* ws = (char*)d_ws;
  unsigned short* xb      = (unsigned short*)(ws);
  unsigned short* Wall    = (unsigned short*)(ws + XB_BYTES);
  unsigned short* Yall    = (unsigned short*)(ws + XB_BYTES + WB_BYTES);
  float*          partial = (float*)(ws + XB_BYTES + WB_BYTES + Y_BYTES);

  // 1) cast inputs to bf16
  {
    int n8 = NTOK * DIM / 8;
    cvt_kernel<<<n8 / 256, 256, 0, stream>>>(x, xb, n8);
    int w8 = DIM * DIM / 8;
    cvt_kernel<<<w8 / 256, 256, 0, stream>>>(Wq, Wall + 0*(size_t)DIM*DIM, w8);
    cvt_kernel<<<w8 / 256, 256, 0, stream>>>(Wk, Wall + 1*(size_t)DIM*DIM, w8);
    cvt_kernel<<<w8 / 256, 256, 0, stream>>>(Wv, Wall + 2*(size_t)DIM*DIM, w8);
    cvt_kernel<<<w8 / 256, 256, 0, stream>>>(Wg, Wall + 3*(size_t)DIM*DIM, w8);
  }

  // 2) four GEMMs (z selects weight): Y[z] = x @ W[z]^T + b[z], bf16 out
  gemm_kernel<<<dim3(DIM/128, NTOK/128, 4), 256, 0, stream>>>(
      xb, Wall, bq, bk, bv, bg, Yall);

  const unsigned short* Yq = Yall + 0*(size_t)NTOK*DIM;
  const unsigned short* Yk = Yall + 1*(size_t)NTOK*DIM;
  const unsigned short* Yv = Yall + 2*(size_t)NTOK*DIM;
  const unsigned short* Yg = Yall + 3*(size_t)NTOK*DIM;

  // 3) chunked cumsum of k*v along seq, then gated output
  chunk_sum_kernel<<<dim3(DIM/512, NCH, BATCH), 256, 0, stream>>>(Yk, Yv, partial);
  scan_kernel<<<(BATCH*DIM)/256, 256, 0, stream>>>(partial);
  final_kernel<<<dim3(DIM/512, NCH, BATCH), 256, 0, stream>>>(Yq, Yk, Yv, Yg, partial, out);
}